// Round 1
// baseline (3193.625 us; speedup 1.0000x reference)
//
#include <hip/hip_runtime.h>
#include <math.h>

#define B_ 2
#define T_ 8
#define M_ 512
#define D_ 1024
#define H_ 1024
#define NC_ 1536
#define KNN 8

#define BM 128
#define BN 128
#define BK 16

// ---------------- shared 128x128 tile GEMM core: acc += A(128xK) * B(128xK)^T
template<bool SCALE>
__device__ __forceinline__ void tile_mm(const float* __restrict__ A, int lda,
                                        const float* __restrict__ Bp, int ldb,
                                        int K, float ra, float rb,
                                        float (&acc)[8][8], float* sA, float* sB)
{
  const int tid  = threadIdx.x;
  const int lr   = tid >> 1;        // 0..127 load row
  const int lk   = (tid & 1) * 8;   // 0 or 8
  const int trow = (tid >> 4) * 8;
  const int tcol = (tid & 15) * 8;

  const float* aRow = A + (size_t)lr * lda + lk;
  const float* bRow = Bp + (size_t)lr * ldb + lk;

  float4 a0 = *(const float4*)(aRow);
  float4 a1 = *(const float4*)(aRow + 4);
  float4 b0 = *(const float4*)(bRow);
  float4 b1 = *(const float4*)(bRow + 4);

  for (int k0 = 0; k0 < K; k0 += BK) {
    if (SCALE) {
      a0.x*=ra; a0.y*=ra; a0.z*=ra; a0.w*=ra;
      a1.x*=ra; a1.y*=ra; a1.z*=ra; a1.w*=ra;
      b0.x*=rb; b0.y*=rb; b0.z*=rb; b0.w*=rb;
      b1.x*=rb; b1.y*=rb; b1.z*=rb; b1.w*=rb;
    }
    __syncthreads();
    sA[(lk+0)*BM+lr]=a0.x; sA[(lk+1)*BM+lr]=a0.y; sA[(lk+2)*BM+lr]=a0.z; sA[(lk+3)*BM+lr]=a0.w;
    sA[(lk+4)*BM+lr]=a1.x; sA[(lk+5)*BM+lr]=a1.y; sA[(lk+6)*BM+lr]=a1.z; sA[(lk+7)*BM+lr]=a1.w;
    sB[(lk+0)*BN+lr]=b0.x; sB[(lk+1)*BN+lr]=b0.y; sB[(lk+2)*BN+lr]=b0.z; sB[(lk+3)*BN+lr]=b0.w;
    sB[(lk+4)*BN+lr]=b1.x; sB[(lk+5)*BN+lr]=b1.y; sB[(lk+6)*BN+lr]=b1.z; sB[(lk+7)*BN+lr]=b1.w;
    __syncthreads();
    if (k0 + BK < K) {  // prefetch next K-slab while computing this one
      a0 = *(const float4*)(aRow + k0 + BK);
      a1 = *(const float4*)(aRow + k0 + BK + 4);
      b0 = *(const float4*)(bRow + k0 + BK);
      b1 = *(const float4*)(bRow + k0 + BK + 4);
    }
    #pragma unroll
    for (int kk = 0; kk < BK; ++kk) {
      float4 x0 = *(const float4*)(sA + kk*BM + trow);
      float4 x1 = *(const float4*)(sA + kk*BM + trow + 4);
      float4 y0 = *(const float4*)(sB + kk*BN + tcol);
      float4 y1 = *(const float4*)(sB + kk*BN + tcol + 4);
      float av[8] = {x0.x,x0.y,x0.z,x0.w,x1.x,x1.y,x1.z,x1.w};
      float bv[8] = {y0.x,y0.y,y0.z,y0.w,y1.x,y1.y,y1.z,y1.w};
      #pragma unroll
      for (int i = 0; i < 8; ++i)
        #pragma unroll
        for (int j = 0; j < 8; ++j)
          acc[i][j] = fmaf(av[i], bv[j], acc[i][j]);
    }
  }
}

// ---------------- small kernels ----------------

__global__ __launch_bounds__(256) void k_colsum(const float* __restrict__ Wk,
                                                float* __restrict__ wk_sum) {
  int d = blockIdx.x*256 + threadIdx.x;
  float s = 0.f;
  for (int i = 0; i < D_; ++i) s += Wk[(size_t)i*D_ + d];
  wk_sum[d] = s;
}

__global__ __launch_bounds__(64) void k_s0(const float* __restrict__ z,
                                           const float* __restrict__ Wattq,
                                           float* __restrict__ s0) {
  int bt = blockIdx.x;
  const float* zr = z + (size_t)bt*M_*D_;  // row m=0 of (b,t)
  float p = 0.f;
  for (int d = threadIdx.x; d < D_; d += 64) p += zr[d]*Wattq[d];
  for (int o = 32; o; o >>= 1) p += __shfl_down(p, o, 64);
  if (threadIdx.x == 0) s0[bt] = p;
}

__global__ __launch_bounds__(256) void k_rnorm(const float* __restrict__ z,
                                               float* __restrict__ rn) {
  int row = blockIdx.x;
  const float* zr = z + (size_t)row*D_;
  int tid = threadIdx.x;
  float4 v = *(const float4*)(zr + tid*4);
  float ss = v.x*v.x + v.y*v.y + v.z*v.z + v.w*v.w;
  for (int o=32;o;o>>=1) ss += __shfl_down(ss,o,64);
  __shared__ float ps[4];
  if ((tid&63)==0) ps[tid>>6] = ss;
  __syncthreads();
  if (tid==0) {
    float s = ps[0]+ps[1]+ps[2]+ps[3];
    rn[row] = 1.0f / fmaxf(sqrtf(s), 1e-12f);
  }
}

// sim[bt] (512 x 1536) = zn[b,t] @ zn[b,max(t-w,0)]^T, normalization folded into staging
__global__ __launch_bounds__(256) void k_sim(const float* __restrict__ z,
                                             const float* __restrict__ rn,
                                             float* __restrict__ sim)
{
  __shared__ float sA[BK*BM];
  __shared__ float sB[BK*BN];
  int zi = blockIdx.z;
  int w  = zi % 3;
  int bt = zi / 3;
  int b  = bt / T_;
  int t  = bt % T_;
  int tw = t - w; if (tw < 0) tw = 0;
  int arow0 = bt*M_ + blockIdx.y*BM;
  int brow0 = (b*T_ + tw)*M_ + blockIdx.x*BN;
  const int lr = threadIdx.x >> 1;
  float ra = rn[arow0 + lr];
  float rb = rn[brow0 + lr];
  float acc[8][8];
  #pragma unroll
  for (int i=0;i<8;i++)
    #pragma unroll
    for (int j=0;j<8;j++) acc[i][j]=0.f;
  tile_mm<true>(z + (size_t)arow0*D_, D_, z + (size_t)brow0*D_, D_, D_, ra, rb, acc, sA, sB);
  const int trow = (threadIdx.x >> 4)*8;
  const int tcol = (threadIdx.x & 15)*8;
  float* C = sim + (size_t)bt*M_*NC_;
  int rowbase = blockIdx.y*BM + trow;
  int colbase = w*M_ + blockIdx.x*BN + tcol;
  #pragma unroll
  for (int i=0;i<8;i++) {
    float* cp = C + (size_t)(rowbase+i)*NC_ + colbase;
    *(float4*)(cp)   = make_float4(acc[i][0],acc[i][1],acc[i][2],acc[i][3]);
    *(float4*)(cp+4) = make_float4(acc[i][4],acc[i][5],acc[i][6],acc[i][7]);
  }
}

// generic batched GEMM: C = [A1@B1^T (+ A2@B2^T)] (+bias) (+add)
template<bool DUAL, bool HASBIAS, bool HASADD>
__global__ __launch_bounds__(256) void k_gemm(
    const float* __restrict__ A1, long long a1bs, int lda1,
    const float* __restrict__ B1, int ldb1,
    const float* __restrict__ A2, long long a2bs, int lda2,
    const float* __restrict__ B2, int ldb2,
    const float* __restrict__ bias,
    const float* __restrict__ add, long long addbs, int ldadd,
    float* __restrict__ C, long long cbs, int ldc, int K)
{
  __shared__ float sA[BK*BM];
  __shared__ float sB[BK*BN];
  const int zb = blockIdx.z;
  float acc[8][8];
  #pragma unroll
  for (int i=0;i<8;i++)
    #pragma unroll
    for (int j=0;j<8;j++) acc[i][j]=0.f;
  {
    const float* A  = A1 + (size_t)zb*a1bs + (size_t)blockIdx.y*BM*lda1;
    const float* Bp = B1 + (size_t)blockIdx.x*BN*ldb1;
    tile_mm<false>(A, lda1, Bp, ldb1, K, 0.f, 0.f, acc, sA, sB);
  }
  if constexpr (DUAL) {
    const float* A  = A2 + (size_t)zb*a2bs + (size_t)blockIdx.y*BM*lda2;
    const float* Bp = B2 + (size_t)blockIdx.x*BN*ldb2;
    tile_mm<false>(A, lda2, Bp, ldb2, K, 0.f, 0.f, acc, sA, sB);
  }
  const int trow = (threadIdx.x >> 4)*8;
  const int tcol = (threadIdx.x & 15)*8;
  const int rowbase = blockIdx.y*BM + trow;
  const int colbase = blockIdx.x*BN + tcol;
  float bx[8] = {0,0,0,0,0,0,0,0};
  if constexpr (HASBIAS) {
    float4 u0 = *(const float4*)(bias + colbase);
    float4 u1 = *(const float4*)(bias + colbase + 4);
    bx[0]=u0.x; bx[1]=u0.y; bx[2]=u0.z; bx[3]=u0.w;
    bx[4]=u1.x; bx[5]=u1.y; bx[6]=u1.z; bx[7]=u1.w;
  }
  float* Cb = C + (size_t)zb*cbs;
  const float* addb = nullptr;
  if constexpr (HASADD) addb = add + (size_t)zb*addbs;
  #pragma unroll
  for (int i=0;i<8;i++) {
    float v[8];
    #pragma unroll
    for (int j=0;j<8;j++) v[j] = acc[i][j] + bx[j];
    if constexpr (HASADD) {
      const float* ap = addb + (size_t)(rowbase+i)*ldadd + colbase;
      float4 q0 = *(const float4*)(ap);
      float4 q1 = *(const float4*)(ap+4);
      v[0]+=q0.x; v[1]+=q0.y; v[2]+=q0.z; v[3]+=q0.w;
      v[4]+=q1.x; v[5]+=q1.y; v[6]+=q1.z; v[7]+=q1.w;
    }
    float* cp = Cb + (size_t)(rowbase+i)*ldc + colbase;
    *(float4*)(cp)   = make_float4(v[0],v[1],v[2],v[3]);
    *(float4*)(cp+4) = make_float4(v[4],v[5],v[6],v[7]);
  }
}

// fused per-row: top-8 (stable, desc) -> att softmax -> alpha -> kbar = sum_k alpha_k * z_k
__global__ __launch_bounds__(256) void k_topk(
    const float* __restrict__ z, const float* __restrict__ sim,
    const float* __restrict__ wk_sum, const float* __restrict__ s0,
    float* __restrict__ kbar)
{
  __shared__ float sv[NC_];          // 6 KB
  __shared__ float zr[KNN][D_];      // 32 KB
  __shared__ float redv[4];
  __shared__ int   redi[4];
  __shared__ float selv[KNN];
  __shared__ int   seli[KNN];
  __shared__ float alpha[KNN];
  __shared__ float khs[KNN];

  int r  = blockIdx.x;               // bt*M + m
  int bt = r / M_, m = r % M_;
  int b  = bt / T_, t = bt % T_;
  int tid = threadIdx.x;
  const float* srow = sim + (size_t)bt*M_*NC_ + (size_t)m*NC_;
  int limit = (t >= 2) ? NC_ : ((t == 1) ? 2*M_ : M_);
  for (int i = tid; i < NC_; i += 256) sv[i] = (i < limit) ? srow[i] : -INFINITY;
  __syncthreads();

  for (int k = 0; k < KNN; ++k) {
    float bv = -INFINITY; int bi = 0x7fffffff;
    for (int i = tid; i < NC_; i += 256) {
      float v = sv[i];
      if (v > bv || (v == bv && i < bi)) { bv = v; bi = i; }
    }
    for (int o = 32; o; o >>= 1) {
      float ov = __shfl_down(bv, o, 64);
      int   oi = __shfl_down(bi, o, 64);
      if (ov > bv || (ov == bv && oi < bi)) { bv = ov; bi = oi; }
    }
    if ((tid & 63) == 0) { redv[tid>>6] = bv; redi[tid>>6] = bi; }
    __syncthreads();
    if (tid == 0) {
      bv = redv[0]; bi = redi[0];
      for (int u = 1; u < 4; ++u)
        if (redv[u] > bv || (redv[u] == bv && redi[u] < bi)) { bv = redv[u]; bi = redi[u]; }
      selv[k] = bv; seli[k] = bi; sv[bi] = -INFINITY;
    }
    __syncthreads();
  }

  // gather the 8 selected z rows into LDS
  for (int k = 0; k < KNN; ++k) {
    int idx = seli[k];
    int w = idx >> 9, n = idx & 511;
    int tt = t - w;
    const float* zp = z + ((size_t)((b*T_ + tt)*M_ + n))*D_;
    int d = tid*4;
    float4 v = *(const float4*)(zp + d);
    zr[k][d] = v.x; zr[k][d+1] = v.y; zr[k][d+2] = v.z; zr[k][d+3] = v.w;
  }
  __syncthreads();

  // kh_sum[k] = z_k . wk_sum
  for (int k = 0; k < KNN; ++k) {
    int d = tid*4;
    float p = zr[k][d]*wk_sum[d] + zr[k][d+1]*wk_sum[d+1]
            + zr[k][d+2]*wk_sum[d+2] + zr[k][d+3]*wk_sum[d+3];
    for (int o = 32; o; o >>= 1) p += __shfl_down(p, o, 64);
    if ((tid & 63) == 0) redv[tid>>6] = p;
    __syncthreads();
    if (tid == 0) khs[k] = redv[0]+redv[1]+redv[2]+redv[3];
    __syncthreads();
  }

  if (tid == 0) {
    float s0v = s0[bt];
    float a[KNN]; float mx = -INFINITY;
    for (int k = 0; k < KNN; ++k) { a[k] = s0v*khs[k]; mx = fmaxf(mx, a[k]); }
    float den = 0.f;
    for (int k = 0; k < KNN; ++k) { a[k] = expf(a[k]-mx); den += a[k]; }
    for (int k = 0; k < KNN; ++k) alpha[k] = 0.5f*selv[k] + 0.5f*(a[k]/den);
  }
  __syncthreads();

  {
    int d = tid*4;
    float o0=0.f,o1=0.f,o2=0.f,o3=0.f;
    #pragma unroll
    for (int k = 0; k < KNN; ++k) {
      float al = alpha[k];
      o0 = fmaf(al, zr[k][d],   o0);
      o1 = fmaf(al, zr[k][d+1], o1);
      o2 = fmaf(al, zr[k][d+2], o2);
      o3 = fmaf(al, zr[k][d+3], o3);
    }
    *(float4*)(kbar + (size_t)r*D_ + d) = make_float4(o0,o1,o2,o3);
  }
}

__global__ __launch_bounds__(256) void k_ln(float* __restrict__ X,
                                            const float* __restrict__ lw,
                                            const float* __restrict__ lb) {
  int r = blockIdx.x, tid = threadIdx.x;
  float* xp = X + (size_t)r*D_;
  int d = tid*4;
  float4 v = *(const float4*)(xp + d);
  float s  = v.x+v.y+v.z+v.w;
  float ss = v.x*v.x+v.y*v.y+v.z*v.z+v.w*v.w;
  for (int o=32;o;o>>=1){ s += __shfl_down(s,o,64); ss += __shfl_down(ss,o,64); }
  __shared__ float rs[4], rss[4];
  if ((tid&63)==0){ rs[tid>>6]=s; rss[tid>>6]=ss; }
  __syncthreads();
  float mu  = (rs[0]+rs[1]+rs[2]+rs[3]) * (1.f/D_);
  float var = (rss[0]+rss[1]+rss[2]+rss[3]) * (1.f/D_) - mu*mu;
  float rstd = rsqrtf(var + 1e-5f);
  float4 w  = *(const float4*)(lw+d);
  float4 bb = *(const float4*)(lb+d);
  v.x = (v.x-mu)*rstd*w.x + bb.x;
  v.y = (v.y-mu)*rstd*w.y + bb.y;
  v.z = (v.z-mu)*rstd*w.z + bb.z;
  v.w = (v.w-mu)*rstd*w.w + bb.w;
  *(float4*)(xp+d) = v;
}

__global__ __launch_bounds__(256) void k_gru(
    const float* __restrict__ gi, const float* __restrict__ gh,
    float* __restrict__ mem, float* __restrict__ memh, int t)
{
  int gid = blockIdx.x*256 + threadIdx.x;   // 0 .. 1024*1024-1
  int row = gid >> 10, h = gid & 1023;
  int b = row >> 9, m = row & 511;
  size_t girow = ((size_t)((b*T_ + t)*M_ + m))*(3*H_);
  float ir  = gi[girow + h];
  float iz  = gi[girow + H_ + h];
  float in_ = gi[girow + 2*H_ + h];
  size_t ghrow = (size_t)row*(3*H_);
  float hr = gh[ghrow + h];
  float hz = gh[ghrow + H_ + h];
  float hn = gh[ghrow + 2*H_ + h];
  float rg = 1.f/(1.f+expf(-(ir+hr)));
  float zg = 1.f/(1.f+expf(-(iz+hz)));
  float n  = tanhf(in_ + rg*hn);
  float mold = mem[gid];
  float mnew = (1.f-zg)*n + zg*mold;
  mem[gid] = mnew;
  memh[((size_t)((b*T_ + t)*M_ + m))*H_ + h] = mnew;   // (b,t,m,h) order
}

extern "C" void kernel_launch(void* const* d_in, const int* in_sizes, int n_in,
                              void* d_out, int out_size, void* d_ws, size_t ws_size,
                              hipStream_t stream) {
  (void)in_sizes; (void)n_in; (void)out_size; (void)ws_size;
  const float* z      = (const float*)d_in[0];
  const float* Wq     = (const float*)d_in[1];
  const float* Wv     = (const float*)d_in[2];
  const float* Wout   = (const float*)d_in[3];
  const float* ln_w   = (const float*)d_in[4];
  const float* ln_b   = (const float*)d_in[5];
  const float* Watt_q = (const float*)d_in[6];
  const float* Watt_k = (const float*)d_in[7];
  const float* W_ih   = (const float*)d_in[8];
  const float* W_hh   = (const float*)d_in[9];
  const float* b_ih   = (const float*)d_in[10];
  const float* b_hh   = (const float*)d_in[11];
  const float* W_mf   = (const float*)d_in[12];
  const float* b_mf   = (const float*)d_in[13];
  float* out = (float*)d_out;
  float* ws  = (float*)d_ws;

  // workspace layout (floats) — overlays: sim->GI, kbar->INP, zn folded into sim staging
  float* X    = ws;                    // 8192*1024
  float* sim  = ws + 8388608;          // 16*512*1536 = 12,582,912 (region sized 25,165,824)
  float* GI   = ws + 8388608;          // 8192*3072 (overlays sim after topk)
  float* kbar = ws + 33554432;         // 8192*1024
  float* INP  = kbar;                  // overlays kbar after X computed
  float* gs   = ws + 41943040;         // 1024*3072
  float* mem  = ws + 45088768;         // 1024*1024
  float* memh = ws + 46137344;         // 8*1024*1024 in (b,t,m,h) order
  float* wks  = ws + 54525952;         // 1024
  float* s0   = ws + 54526976;         // 16
  float* rn   = ws + 54526992;         // 8192
  // total: 54,535,184 floats ~ 208 MiB

  k_colsum<<<dim3(4), dim3(256), 0, stream>>>(Watt_k, wks);
  k_s0    <<<dim3(16), dim3(64), 0, stream>>>(z, Watt_q, s0);
  k_rnorm <<<dim3(8192), dim3(256), 0, stream>>>(z, rn);

  // sim (fp32 — topk selection must be exact)
  k_sim<<<dim3(4,4,48), dim3(256), 0, stream>>>(z, rn, sim);

  // topk + attention + kbar
  k_topk<<<dim3(8192), dim3(256), 0, stream>>>(z, sim, wks, s0, kbar);

  // X = kbar@Wv^T + z@Wq^T   (dual GEMM, 8192x1024, K=1024 each)
  k_gemm<true,false,false><<<dim3(8,64,1), dim3(256), 0, stream>>>(
      kbar, 0, D_, Wv, D_, z, 0, D_, Wq, D_,
      nullptr, nullptr, 0, 0, X, 0, D_, D_);

  k_ln<<<dim3(8192), dim3(256), 0, stream>>>(X, ln_w, ln_b);

  // INP = X@Wout^T
  k_gemm<false,false,false><<<dim3(8,64,1), dim3(256), 0, stream>>>(
      X, 0, D_, Wout, D_, nullptr, 0, 0, nullptr, 0,
      nullptr, nullptr, 0, 0, INP, 0, D_, D_);

  // GI = INP@W_ih^T + b_ih   (8192x3072) — overlays sim region
  k_gemm<false,true,false><<<dim3(24,64,1), dim3(256), 0, stream>>>(
      INP, 0, D_, W_ih, D_, nullptr, 0, 0, nullptr, 0,
      b_ih, nullptr, 0, 0, GI, 0, 3*H_, D_);

  hipMemsetAsync(mem, 0, (size_t)1048576*sizeof(float), stream);

  for (int t = 0; t < T_; ++t) {
    // gs = mem@W_hh^T + b_hh   (1024x3072)
    k_gemm<false,true,false><<<dim3(24,8,1), dim3(256), 0, stream>>>(
        mem, 0, H_, W_hh, H_, nullptr, 0, 0, nullptr, 0,
        b_hh, nullptr, 0, 0, gs, 0, 3*H_, H_);
    k_gru<<<dim3(4096), dim3(256), 0, stream>>>(GI, gs, mem, memh, t);
  }

  // OUT = z + memh@W_mf^T + b_mf  (batched over the 16 (b,t) slabs)
  k_gemm<false,true,true><<<dim3(8,4,16), dim3(256), 0, stream>>>(
      memh, (long long)M_*H_, H_, W_mf, H_, nullptr, 0, 0, nullptr, 0,
      b_mf, z, (long long)M_*D_, D_, out, (long long)M_*D_, D_, H_);

  // final mem -> tail of d_out
  hipMemcpyAsync(out + (size_t)B_*T_*M_*D_, mem, (size_t)1048576*sizeof(float),
                 hipMemcpyDeviceToDevice, stream);
}

// Round 2
// 1136.048 us; speedup vs baseline: 2.8112x; 2.8112x over previous
//
#include <hip/hip_runtime.h>
#include <hip/hip_bf16.h>
#include <math.h>

#define B_ 2
#define T_ 8
#define M_ 512
#define D_ 1024
#define H_ 1024
#define NC_ 1536
#define KNN 8

#define BM 128
#define BN 128
#define BK 16

typedef __hip_bfloat16 bf16;
typedef short v8s __attribute__((ext_vector_type(8)));   // 8 bf16 (4 VGPRs)
typedef float v4f __attribute__((ext_vector_type(4)));   // MFMA acc

// ---------------- async global->LDS 16B (wave-uniform base + lane*16 layout)
__device__ __forceinline__ void async16(const void* g, void* l) {
  __builtin_amdgcn_global_load_lds(
      (const __attribute__((address_space(1))) void*)g,
      (__attribute__((address_space(3))) void*)l, 16, 0, 0);
}

// ---------------- fp32 tile core (sim only: topk selection must stay fp32)
template<bool SCALE>
__device__ __forceinline__ void tile_mm(const float* __restrict__ A, int lda,
                                        const float* __restrict__ Bp, int ldb,
                                        int K, float ra, float rb,
                                        float (&acc)[8][8], float* sA, float* sB)
{
  const int tid  = threadIdx.x;
  const int lr   = tid >> 1;
  const int lk   = (tid & 1) * 8;
  const int trow = (tid >> 4) * 8;
  const int tcol = (tid & 15) * 8;

  const float* aRow = A + (size_t)lr * lda + lk;
  const float* bRow = Bp + (size_t)lr * ldb + lk;

  float4 a0 = *(const float4*)(aRow);
  float4 a1 = *(const float4*)(aRow + 4);
  float4 b0 = *(const float4*)(bRow);
  float4 b1 = *(const float4*)(bRow + 4);

  for (int k0 = 0; k0 < K; k0 += BK) {
    if (SCALE) {
      a0.x*=ra; a0.y*=ra; a0.z*=ra; a0.w*=ra;
      a1.x*=ra; a1.y*=ra; a1.z*=ra; a1.w*=ra;
      b0.x*=rb; b0.y*=rb; b0.z*=rb; b0.w*=rb;
      b1.x*=rb; b1.y*=rb; b1.z*=rb; b1.w*=rb;
    }
    __syncthreads();
    sA[(lk+0)*BM+lr]=a0.x; sA[(lk+1)*BM+lr]=a0.y; sA[(lk+2)*BM+lr]=a0.z; sA[(lk+3)*BM+lr]=a0.w;
    sA[(lk+4)*BM+lr]=a1.x; sA[(lk+5)*BM+lr]=a1.y; sA[(lk+6)*BM+lr]=a1.z; sA[(lk+7)*BM+lr]=a1.w;
    sB[(lk+0)*BN+lr]=b0.x; sB[(lk+1)*BN+lr]=b0.y; sB[(lk+2)*BN+lr]=b0.z; sB[(lk+3)*BN+lr]=b0.w;
    sB[(lk+4)*BN+lr]=b1.x; sB[(lk+5)*BN+lr]=b1.y; sB[(lk+6)*BN+lr]=b1.z; sB[(lk+7)*BN+lr]=b1.w;
    __syncthreads();
    if (k0 + BK < K) {
      a0 = *(const float4*)(aRow + k0 + BK);
      a1 = *(const float4*)(aRow + k0 + BK + 4);
      b0 = *(const float4*)(bRow + k0 + BK);
      b1 = *(const float4*)(bRow + k0 + BK + 4);
    }
    #pragma unroll
    for (int kk = 0; kk < BK; ++kk) {
      float4 x0 = *(const float4*)(sA + kk*BM + trow);
      float4 x1 = *(const float4*)(sA + kk*BM + trow + 4);
      float4 y0 = *(const float4*)(sB + kk*BN + tcol);
      float4 y1 = *(const float4*)(sB + kk*BN + tcol + 4);
      float av[8] = {x0.x,x0.y,x0.z,x0.w,x1.x,x1.y,x1.z,x1.w};
      float bv[8] = {y0.x,y0.y,y0.z,y0.w,y1.x,y1.y,y1.z,y1.w};
      #pragma unroll
      for (int i = 0; i < 8; ++i)
        #pragma unroll
        for (int j = 0; j < 8; ++j)
          acc[i][j] = fmaf(av[i], bv[j], acc[i][j]);
    }
  }
}

// ---------------- bf16 MFMA tile core: acc += A(128xK) * B(128xK)^T
// LDS tile row-major [128][32] bf16, 16B chunks XOR-swizzled: slot (r,kc) holds
// global k-chunk kc ^ ((r>>1)&3)  -> ds_read_b128 frag reads are 2 lanes/bank (free).
__device__ __forceinline__ void mfma_loop(const bf16* __restrict__ A,
                                          const bf16* __restrict__ Bp,
                                          int K, v4f (&acc)[4][4],
                                          bf16* sA, bf16* sB)
{
  const int tid  = threadIdx.x;
  const int lane = tid & 63;
  const int wave = tid >> 6;
  const int quad = lane >> 4;
  const int l15  = lane & 15;
  const int wr = (wave >> 1) * 64;
  const int wc = (wave & 1) * 64;

  // staging: thread handles 16B chunks c=tid and c+256 of both A and B tiles
  const int r0 = tid >> 2, g0 = (tid & 3) ^ ((r0 >> 1) & 3);
  const int c1 = tid + 256;
  const int r1 = c1 >> 2,  g1 = (c1 & 3) ^ ((r1 >> 1) & 3);

  const bf16* a0p = A  + (size_t)r0*K + g0*8;
  const bf16* a1p = A  + (size_t)r1*K + g1*8;
  const bf16* b0p = Bp + (size_t)r0*K + g0*8;
  const bf16* b1p = Bp + (size_t)r1*K + g1*8;
  bf16* la0 = sA + tid*8;  bf16* la1 = sA + c1*8;
  bf16* lb0 = sB + tid*8;  bf16* lb1 = sB + c1*8;

  // fragment LDS offsets (bf16 element units)
  int aoff[4], boff[4];
  #pragma unroll
  for (int i = 0; i < 4; ++i) {
    int ra = wr + i*16 + l15;
    aoff[i] = (ra*4 + (quad ^ ((ra >> 1) & 3))) * 8;
    int rb = wc + i*16 + l15;
    boff[i] = (rb*4 + (quad ^ ((rb >> 1) & 3))) * 8;
  }

  for (int k0 = 0; k0 < K; k0 += 32) {
    __syncthreads();
    async16(a0p + k0, la0);
    async16(a1p + k0, la1);
    async16(b0p + k0, lb0);
    async16(b1p + k0, lb1);
    __syncthreads();   // compiler emits s_waitcnt vmcnt(0) before s_barrier
    v8s af[4], bfr[4];
    #pragma unroll
    for (int i = 0; i < 4; ++i) af[i]  = *(const v8s*)(sA + aoff[i]);
    #pragma unroll
    for (int i = 0; i < 4; ++i) bfr[i] = *(const v8s*)(sB + boff[i]);
    #pragma unroll
    for (int mi = 0; mi < 4; ++mi)
      #pragma unroll
      for (int ni = 0; ni < 4; ++ni)
        acc[mi][ni] = __builtin_amdgcn_mfma_f32_16x16x32_bf16(
            af[mi], bfr[ni], acc[mi][ni], 0, 0, 0);
  }
}

// C = A1@B1^T (+A2@B2^T) (+bias) (+add) ; all dims multiples of 128; ldc=N, ld{a,b}=K
template<bool DUAL, bool HASBIAS, bool HASADD, bool OUTBF>
__global__ __launch_bounds__(256) void k_bgemm(
    const bf16* __restrict__ A1, const bf16* __restrict__ B1,
    const bf16* __restrict__ A2, const bf16* __restrict__ B2,
    const float* __restrict__ bias, const float* __restrict__ add,
    void* __restrict__ Cv, int N, int K)
{
  __shared__ bf16 sA[128*32];
  __shared__ bf16 sB[128*32];
  v4f acc[4][4];
  #pragma unroll
  for (int i = 0; i < 4; ++i)
    #pragma unroll
    for (int j = 0; j < 4; ++j) acc[i][j] = (v4f){0.f,0.f,0.f,0.f};

  const int row0 = blockIdx.y * 128, col0 = blockIdx.x * 128;
  mfma_loop(A1 + (size_t)row0*K, B1 + (size_t)col0*K, K, acc, sA, sB);
  if constexpr (DUAL)
    mfma_loop(A2 + (size_t)row0*K, B2 + (size_t)col0*K, K, acc, sA, sB);

  const int tid = threadIdx.x, lane = tid & 63, wave = tid >> 6;
  const int quad = lane >> 4, l15 = lane & 15;
  const int wr = (wave >> 1) * 64, wc = (wave & 1) * 64;

  #pragma unroll
  for (int ni = 0; ni < 4; ++ni) {
    const int col = col0 + wc + ni*16 + l15;
    float bv = 0.f;
    if constexpr (HASBIAS) bv = bias[col];
    #pragma unroll
    for (int mi = 0; mi < 4; ++mi) {
      const int rowb = row0 + wr + mi*16 + quad*4;
      #pragma unroll
      for (int reg = 0; reg < 4; ++reg) {
        const int row = rowb + reg;
        float v = acc[mi][ni][reg] + bv;
        if constexpr (HASADD) v += add[(size_t)row*N + col];
        if constexpr (OUTBF)
          ((bf16*)Cv)[(size_t)row*N + col] = __float2bfloat16(v);
        else
          ((float*)Cv)[(size_t)row*N + col] = v;
      }
    }
  }
}

// ---------------- small kernels ----------------

__global__ __launch_bounds__(256) void k_cast(const float* __restrict__ src,
                                              bf16* __restrict__ dst, int n4) {
  int i = blockIdx.x*256 + threadIdx.x;
  if (i < n4) {
    float4 v = ((const float4*)src)[i];
    bf16* p = dst + (size_t)i*4;
    p[0] = __float2bfloat16(v.x); p[1] = __float2bfloat16(v.y);
    p[2] = __float2bfloat16(v.z); p[3] = __float2bfloat16(v.w);
  }
}

__global__ __launch_bounds__(256) void k_colsum(const float* __restrict__ Wk,
                                                float* __restrict__ wk_sum) {
  int d = blockIdx.x*256 + threadIdx.x;
  float s = 0.f;
  for (int i = 0; i < D_; ++i) s += Wk[(size_t)i*D_ + d];
  wk_sum[d] = s;
}

__global__ __launch_bounds__(64) void k_s0(const float* __restrict__ z,
                                           const float* __restrict__ Wattq,
                                           float* __restrict__ s0) {
  int bt = blockIdx.x;
  const float* zr = z + (size_t)bt*M_*D_;
  float p = 0.f;
  for (int d = threadIdx.x; d < D_; d += 64) p += zr[d]*Wattq[d];
  for (int o = 32; o; o >>= 1) p += __shfl_down(p, o, 64);
  if (threadIdx.x == 0) s0[bt] = p;
}

__global__ __launch_bounds__(256) void k_rnorm(const float* __restrict__ z,
                                               float* __restrict__ rn) {
  int row = blockIdx.x;
  const float* zr = z + (size_t)row*D_;
  int tid = threadIdx.x;
  float4 v = *(const float4*)(zr + tid*4);
  float ss = v.x*v.x + v.y*v.y + v.z*v.z + v.w*v.w;
  for (int o=32;o;o>>=1) ss += __shfl_down(ss,o,64);
  __shared__ float ps[4];
  if ((tid&63)==0) ps[tid>>6] = ss;
  __syncthreads();
  if (tid==0) {
    float s = ps[0]+ps[1]+ps[2]+ps[3];
    rn[row] = 1.0f / fmaxf(sqrtf(s), 1e-12f);
  }
}

__global__ __launch_bounds__(256) void k_sim(const float* __restrict__ z,
                                             const float* __restrict__ rn,
                                             float* __restrict__ sim)
{
  __shared__ float sA[BK*BM];
  __shared__ float sB[BK*BN];
  int zi = blockIdx.z;
  int w  = zi % 3;
  int bt = zi / 3;
  int b  = bt / T_;
  int t  = bt % T_;
  int tw = t - w; if (tw < 0) tw = 0;
  int arow0 = bt*M_ + blockIdx.y*BM;
  int brow0 = (b*T_ + tw)*M_ + blockIdx.x*BN;
  const int lr = threadIdx.x >> 1;
  float ra = rn[arow0 + lr];
  float rb = rn[brow0 + lr];
  float acc[8][8];
  #pragma unroll
  for (int i=0;i<8;i++)
    #pragma unroll
    for (int j=0;j<8;j++) acc[i][j]=0.f;
  tile_mm<true>(z + (size_t)arow0*D_, D_, z + (size_t)brow0*D_, D_, D_, ra, rb, acc, sA, sB);
  const int trow = (threadIdx.x >> 4)*8;
  const int tcol = (threadIdx.x & 15)*8;
  float* C = sim + (size_t)bt*M_*NC_;
  int rowbase = blockIdx.y*BM + trow;
  int colbase = w*M_ + blockIdx.x*BN + tcol;
  #pragma unroll
  for (int i=0;i<8;i++) {
    float* cp = C + (size_t)(rowbase+i)*NC_ + colbase;
    *(float4*)(cp)   = make_float4(acc[i][0],acc[i][1],acc[i][2],acc[i][3]);
    *(float4*)(cp+4) = make_float4(acc[i][4],acc[i][5],acc[i][6],acc[i][7]);
  }
}

// fused per-row: top-8 -> att softmax -> alpha -> kbar(bf16) = sum alpha_k z_k
__global__ __launch_bounds__(256) void k_topk(
    const float* __restrict__ z, const float* __restrict__ sim,
    const float* __restrict__ wk_sum, const float* __restrict__ s0,
    bf16* __restrict__ kbarb)
{
  __shared__ float sv[NC_];
  __shared__ float zr[KNN][D_];
  __shared__ float redv[4];
  __shared__ int   redi[4];
  __shared__ float selv[KNN];
  __shared__ int   seli[KNN];
  __shared__ float alpha[KNN];
  __shared__ float khs[KNN];

  int r  = blockIdx.x;
  int bt = r / M_, m = r % M_;
  int b  = bt / T_, t = bt % T_;
  int tid = threadIdx.x;
  const float* srow = sim + (size_t)bt*M_*NC_ + (size_t)m*NC_;
  int limit = (t >= 2) ? NC_ : ((t == 1) ? 2*M_ : M_);
  for (int i = tid; i < NC_; i += 256) sv[i] = (i < limit) ? srow[i] : -INFINITY;
  __syncthreads();

  for (int k = 0; k < KNN; ++k) {
    float bv = -INFINITY; int bi = 0x7fffffff;
    for (int i = tid; i < NC_; i += 256) {
      float v = sv[i];
      if (v > bv || (v == bv && i < bi)) { bv = v; bi = i; }
    }
    for (int o = 32; o; o >>= 1) {
      float ov = __shfl_down(bv, o, 64);
      int   oi = __shfl_down(bi, o, 64);
      if (ov > bv || (ov == bv && oi < bi)) { bv = ov; bi = oi; }
    }
    if ((tid & 63) == 0) { redv[tid>>6] = bv; redi[tid>>6] = bi; }
    __syncthreads();
    if (tid == 0) {
      bv = redv[0]; bi = redi[0];
      for (int u = 1; u < 4; ++u)
        if (redv[u] > bv || (redv[u] == bv && redi[u] < bi)) { bv = redv[u]; bi = redi[u]; }
      selv[k] = bv; seli[k] = bi; sv[bi] = -INFINITY;
    }
    __syncthreads();
  }

  for (int k = 0; k < KNN; ++k) {
    int idx = seli[k];
    int w = idx >> 9, n = idx & 511;
    int tt = t - w;
    const float* zp = z + ((size_t)((b*T_ + tt)*M_ + n))*D_;
    int d = tid*4;
    float4 v = *(const float4*)(zp + d);
    zr[k][d] = v.x; zr[k][d+1] = v.y; zr[k][d+2] = v.z; zr[k][d+3] = v.w;
  }
  __syncthreads();

  for (int k = 0; k < KNN; ++k) {
    int d = tid*4;
    float p = zr[k][d]*wk_sum[d] + zr[k][d+1]*wk_sum[d+1]
            + zr[k][d+2]*wk_sum[d+2] + zr[k][d+3]*wk_sum[d+3];
    for (int o = 32; o; o >>= 1) p += __shfl_down(p, o, 64);
    if ((tid & 63) == 0) redv[tid>>6] = p;
    __syncthreads();
    if (tid == 0) khs[k] = redv[0]+redv[1]+redv[2]+redv[3];
    __syncthreads();
  }

  if (tid == 0) {
    float s0v = s0[bt];
    float a[KNN]; float mx = -INFINITY;
    for (int k = 0; k < KNN; ++k) { a[k] = s0v*khs[k]; mx = fmaxf(mx, a[k]); }
    float den = 0.f;
    for (int k = 0; k < KNN; ++k) { a[k] = expf(a[k]-mx); den += a[k]; }
    for (int k = 0; k < KNN; ++k) alpha[k] = 0.5f*selv[k] + 0.5f*(a[k]/den);
  }
  __syncthreads();

  {
    int d = tid*4;
    float o0=0.f,o1=0.f,o2=0.f,o3=0.f;
    #pragma unroll
    for (int k = 0; k < KNN; ++k) {
      float al = alpha[k];
      o0 = fmaf(al, zr[k][d],   o0);
      o1 = fmaf(al, zr[k][d+1], o1);
      o2 = fmaf(al, zr[k][d+2], o2);
      o3 = fmaf(al, zr[k][d+3], o3);
    }
    bf16* kp = kbarb + (size_t)r*D_ + d;
    kp[0] = __float2bfloat16(o0); kp[1] = __float2bfloat16(o1);
    kp[2] = __float2bfloat16(o2); kp[3] = __float2bfloat16(o3);
  }
}

// LN: read fp32 X, write bf16 Xb
__global__ __launch_bounds__(256) void k_ln(const float* __restrict__ X,
                                            const float* __restrict__ lw,
                                            const float* __restrict__ lb,
                                            bf16* __restrict__ Xb) {
  int r = blockIdx.x, tid = threadIdx.x;
  const float* xp = X + (size_t)r*D_;
  int d = tid*4;
  float4 v = *(const float4*)(xp + d);
  float s  = v.x+v.y+v.z+v.w;
  float ss = v.x*v.x+v.y*v.y+v.z*v.z+v.w*v.w;
  for (int o=32;o;o>>=1){ s += __shfl_down(s,o,64); ss += __shfl_down(ss,o,64); }
  __shared__ float rs[4], rss[4];
  if ((tid&63)==0){ rs[tid>>6]=s; rss[tid>>6]=ss; }
  __syncthreads();
  float mu  = (rs[0]+rs[1]+rs[2]+rs[3]) * (1.f/D_);
  float var = (rss[0]+rss[1]+rss[2]+rss[3]) * (1.f/D_) - mu*mu;
  float rstd = rsqrtf(var + 1e-5f);
  float4 w  = *(const float4*)(lw+d);
  float4 bb = *(const float4*)(lb+d);
  bf16* op = Xb + (size_t)r*D_ + d;
  op[0] = __float2bfloat16((v.x-mu)*rstd*w.x + bb.x);
  op[1] = __float2bfloat16((v.y-mu)*rstd*w.y + bb.y);
  op[2] = __float2bfloat16((v.z-mu)*rstd*w.z + bb.z);
  op[3] = __float2bfloat16((v.w-mu)*rstd*w.w + bb.w);
}

__global__ __launch_bounds__(256) void k_gru(
    const float* __restrict__ gi, const float* __restrict__ gh,
    float* __restrict__ mem, bf16* __restrict__ memb,
    bf16* __restrict__ memhb, int t)
{
  int gid = blockIdx.x*256 + threadIdx.x;
  int row = gid >> 10, h = gid & 1023;
  int b = row >> 9, m = row & 511;
  size_t girow = ((size_t)((b*T_ + t)*M_ + m))*(3*H_);
  float ir  = gi[girow + h];
  float iz  = gi[girow + H_ + h];
  float in_ = gi[girow + 2*H_ + h];
  size_t ghrow = (size_t)row*(3*H_);
  float hr = gh[ghrow + h];
  float hz = gh[ghrow + H_ + h];
  float hn = gh[ghrow + 2*H_ + h];
  float rg = 1.f/(1.f+expf(-(ir+hr)));
  float zg = 1.f/(1.f+expf(-(iz+hz)));
  float n  = tanhf(in_ + rg*hn);
  float mold = mem[gid];
  float mnew = (1.f-zg)*n + zg*mold;
  mem[gid] = mnew;
  memb[gid] = __float2bfloat16(mnew);
  memhb[((size_t)((b*T_ + t)*M_ + m))*H_ + h] = __float2bfloat16(mnew);
}

extern "C" void kernel_launch(void* const* d_in, const int* in_sizes, int n_in,
                              void* d_out, int out_size, void* d_ws, size_t ws_size,
                              hipStream_t stream) {
  (void)in_sizes; (void)n_in; (void)out_size; (void)ws_size;
  const float* z      = (const float*)d_in[0];
  const float* Wq     = (const float*)d_in[1];
  const float* Wv     = (const float*)d_in[2];
  const float* Wout   = (const float*)d_in[3];
  const float* ln_w   = (const float*)d_in[4];
  const float* ln_b   = (const float*)d_in[5];
  const float* Watt_q = (const float*)d_in[6];
  const float* Watt_k = (const float*)d_in[7];
  const float* W_ih   = (const float*)d_in[8];
  const float* W_hh   = (const float*)d_in[9];
  const float* b_ih   = (const float*)d_in[10];
  const float* b_hh   = (const float*)d_in[11];
  const float* W_mf   = (const float*)d_in[12];
  const float* b_mf   = (const float*)d_in[13];
  float* out = (float*)d_out;
  float* ws  = (float*)d_ws;

  // workspace (float offsets). R1 = [sim | X | GI] time-multiplexed.
  float* GI    = ws;                        // 25,165,824 f (8192x3072)
  float* sim   = ws;                        // 12,582,912 f (dead after topk)
  float* X     = ws;                        // 8,388,608 f (written after topk, dead after ln)
  float* gs    = ws + 25165824;             // 3,145,728 f
  float* mem   = ws + 28311552;             // 1,048,576 f
  bf16*  Xb    = (bf16*)(ws + 29360128);    // 8,388,608 bf16
  bf16*  zb    = (bf16*)(ws + 33554432);    // 8,388,608 bf16
  bf16*  kbarb = (bf16*)(ws + 37748736);    // 8,388,608 bf16 (alias INPb)
  bf16*  INPb  = kbarb;
  bf16*  memb  = (bf16*)(ws + 41943040);    // 1,048,576 bf16
  bf16*  memhb = (bf16*)(ws + 42467328);    // 8,388,608 bf16 (b,t,m,h)
  bf16*  Wqb   = (bf16*)(ws + 46661632);
  bf16*  Wvb   = Wqb + 1048576;
  bf16*  Woutb = Wqb + 2097152;
  bf16*  Wihb  = Wqb + 3145728;
  bf16*  Whhb  = Wqb + 6291456;
  bf16*  Wmfb  = Wqb + 9437184;
  float* wks   = ws + 51904512;             // 1024
  float* s0    = ws + 51905536;             // 16
  float* rn    = ws + 51905552;             // 8192
  // end: 51,913,744 floats ~ 207.7 MiB

  // weight + z casts
  k_cast<<<dim3(1024), dim3(256), 0, stream>>>(Wq,   Wqb,   262144);
  k_cast<<<dim3(1024), dim3(256), 0, stream>>>(Wv,   Wvb,   262144);
  k_cast<<<dim3(1024), dim3(256), 0, stream>>>(Wout, Woutb, 262144);
  k_cast<<<dim3(3072), dim3(256), 0, stream>>>(W_ih, Wihb,  786432);
  k_cast<<<dim3(3072), dim3(256), 0, stream>>>(W_hh, Whhb,  786432);
  k_cast<<<dim3(1024), dim3(256), 0, stream>>>(W_mf, Wmfb,  262144);
  k_cast<<<dim3(8192), dim3(256), 0, stream>>>(z,    zb,   2097152);

  k_colsum<<<dim3(4), dim3(256), 0, stream>>>(Watt_k, wks);
  k_s0    <<<dim3(16), dim3(64), 0, stream>>>(z, Watt_q, s0);
  k_rnorm <<<dim3(8192), dim3(256), 0, stream>>>(z, rn);

  // sim (fp32 vector GEMM — selection must match fp32 reference ordering)
  k_sim<<<dim3(4,4,48), dim3(256), 0, stream>>>(z, rn, sim);

  // topk + attention + kbar (bf16)
  k_topk<<<dim3(8192), dim3(256), 0, stream>>>(z, sim, wks, s0, kbarb);

  // X = kbar@Wv^T + z@Wq^T  (fp32 out)
  k_bgemm<true,false,false,false><<<dim3(8,64), dim3(256), 0, stream>>>(
      kbarb, Wvb, zb, Wqb, nullptr, nullptr, X, D_, D_);

  // LN -> Xb (bf16)
  k_ln<<<dim3(8192), dim3(256), 0, stream>>>(X, ln_w, ln_b, Xb);

  // INP = X@Wout^T -> bf16
  k_bgemm<false,false,false,true><<<dim3(8,64), dim3(256), 0, stream>>>(
      Xb, Woutb, nullptr, nullptr, nullptr, nullptr, INPb, D_, D_);

  // GI = INP@W_ih^T + b_ih (fp32, overlays sim/X region)
  k_bgemm<false,true,false,false><<<dim3(24,64), dim3(256), 0, stream>>>(
      INPb, Wihb, nullptr, nullptr, b_ih, nullptr, GI, 3*H_, D_);

  hipMemsetAsync(mem,  0, (size_t)1048576*sizeof(float), stream);
  hipMemsetAsync(memb, 0, (size_t)1048576*sizeof(bf16),  stream);

  for (int t = 0; t < T_; ++t) {
    // gs = mem@W_hh^T + b_hh (1024x3072)
    k_bgemm<false,true,false,false><<<dim3(24,8), dim3(256), 0, stream>>>(
        memb, Whhb, nullptr, nullptr, b_hh, nullptr, gs, 3*H_, H_);
    k_gru<<<dim3(4096), dim3(256), 0, stream>>>(GI, gs, mem, memb, memhb, t);
  }

  // OUT = z + memh@W_mf^T + b_mf  (single flat 8192x1024 GEMM)
  k_bgemm<false,true,true,false><<<dim3(8,64), dim3(256), 0, stream>>>(
      memhb, Wmfb, nullptr, nullptr, b_mf, z, out, D_, H_);

  hipMemcpyAsync(out + (size_t)B_*T_*M_*D_, mem, (size_t)1048576*sizeof(float),
                 hipMemcpyDeviceToDevice, stream);
}

// Round 3
// 827.005 us; speedup vs baseline: 3.8617x; 1.3737x over previous
//
#include <hip/hip_runtime.h>
#include <hip/hip_bf16.h>
#include <math.h>

#define B_ 2
#define T_ 8
#define M_ 512
#define D_ 1024
#define H_ 1024
#define NC_ 1536
#define KNN 8

typedef __hip_bfloat16 bf16;
typedef short v8s __attribute__((ext_vector_type(8)));   // 8 bf16 (4 VGPRs)
typedef float v4f __attribute__((ext_vector_type(4)));   // MFMA acc

__device__ __forceinline__ float b2f(short s) {
  union { unsigned u; float f; } x; x.u = ((unsigned)(unsigned short)s) << 16; return x.f;
}

// ---------------- async global->LDS 16B (wave-uniform base + lane*16 layout)
__device__ __forceinline__ void async16(const void* g, void* l) {
  __builtin_amdgcn_global_load_lds(
      (const __attribute__((address_space(1))) void*)g,
      (__attribute__((address_space(3))) void*)l, 16, 0, 0);
}

// ---------------- bf16 MFMA tile core: acc += A(128xK) * B(128xK)^T
// LDS tile row-major [128][32] bf16, 16B chunks XOR-swizzled: slot (r,kc) holds
// global k-chunk kc ^ ((r>>1)&3)  -> ds_read_b128 frag reads are 2 lanes/bank (free).
__device__ __forceinline__ void mfma_loop(const bf16* __restrict__ A,
                                          const bf16* __restrict__ Bp,
                                          int K, v4f (&acc)[4][4],
                                          bf16* sA, bf16* sB)
{
  const int tid  = threadIdx.x;
  const int lane = tid & 63;
  const int wave = tid >> 6;
  const int quad = lane >> 4;
  const int l15  = lane & 15;
  const int wr = (wave >> 1) * 64;
  const int wc = (wave & 1) * 64;

  const int r0 = tid >> 2, g0 = (tid & 3) ^ ((r0 >> 1) & 3);
  const int c1 = tid + 256;
  const int r1 = c1 >> 2,  g1 = (c1 & 3) ^ ((r1 >> 1) & 3);

  const bf16* a0p = A  + (size_t)r0*K + g0*8;
  const bf16* a1p = A  + (size_t)r1*K + g1*8;
  const bf16* b0p = Bp + (size_t)r0*K + g0*8;
  const bf16* b1p = Bp + (size_t)r1*K + g1*8;
  bf16* la0 = sA + tid*8;  bf16* la1 = sA + c1*8;
  bf16* lb0 = sB + tid*8;  bf16* lb1 = sB + c1*8;

  int aoff[4], boff[4];
  #pragma unroll
  for (int i = 0; i < 4; ++i) {
    int ra = wr + i*16 + l15;
    aoff[i] = (ra*4 + (quad ^ ((ra >> 1) & 3))) * 8;
    int rb = wc + i*16 + l15;
    boff[i] = (rb*4 + (quad ^ ((rb >> 1) & 3))) * 8;
  }

  for (int k0 = 0; k0 < K; k0 += 32) {
    __syncthreads();
    async16(a0p + k0, la0);
    async16(a1p + k0, la1);
    async16(b0p + k0, lb0);
    async16(b1p + k0, lb1);
    __syncthreads();
    v8s af[4], bfr[4];
    #pragma unroll
    for (int i = 0; i < 4; ++i) af[i]  = *(const v8s*)(sA + aoff[i]);
    #pragma unroll
    for (int i = 0; i < 4; ++i) bfr[i] = *(const v8s*)(sB + boff[i]);
    #pragma unroll
    for (int mi = 0; mi < 4; ++mi)
      #pragma unroll
      for (int ni = 0; ni < 4; ++ni)
        acc[mi][ni] = __builtin_amdgcn_mfma_f32_16x16x32_bf16(
            af[mi], bfr[ni], acc[mi][ni], 0, 0, 0);
  }
}

// C = A1@B1^T (+A2@B2^T) (+bias) (+add) ; dims multiples of 128; ldc=N, ld{a,b}=K
template<bool DUAL, bool HASBIAS, bool HASADD, bool OUTBF>
__global__ __launch_bounds__(256) void k_bgemm(
    const bf16* __restrict__ A1, const bf16* __restrict__ B1,
    const bf16* __restrict__ A2, const bf16* __restrict__ B2,
    const float* __restrict__ bias, const float* __restrict__ add,
    void* __restrict__ Cv, int N, int K)
{
  __shared__ bf16 sA[128*32];
  __shared__ bf16 sB[128*32];
  v4f acc[4][4];
  #pragma unroll
  for (int i = 0; i < 4; ++i)
    #pragma unroll
    for (int j = 0; j < 4; ++j) acc[i][j] = (v4f){0.f,0.f,0.f,0.f};

  const int row0 = blockIdx.y * 128, col0 = blockIdx.x * 128;
  mfma_loop(A1 + (size_t)row0*K, B1 + (size_t)col0*K, K, acc, sA, sB);
  if constexpr (DUAL)
    mfma_loop(A2 + (size_t)row0*K, B2 + (size_t)col0*K, K, acc, sA, sB);

  const int tid = threadIdx.x, lane = tid & 63, wave = tid >> 6;
  const int quad = lane >> 4, l15 = lane & 15;
  const int wr = (wave >> 1) * 64, wc = (wave & 1) * 64;

  #pragma unroll
  for (int ni = 0; ni < 4; ++ni) {
    const int col = col0 + wc + ni*16 + l15;
    float bv = 0.f;
    if constexpr (HASBIAS) bv = bias[col];
    #pragma unroll
    for (int mi = 0; mi < 4; ++mi) {
      const int rowb = row0 + wr + mi*16 + quad*4;
      #pragma unroll
      for (int reg = 0; reg < 4; ++reg) {
        const int row = rowb + reg;
        float v = acc[mi][ni][reg] + bv;
        if constexpr (HASADD) v += add[(size_t)row*N + col];
        if constexpr (OUTBF)
          ((bf16*)Cv)[(size_t)row*N + col] = __float2bfloat16(v);
        else
          ((float*)Cv)[(size_t)row*N + col] = v;
      }
    }
  }
}

// ---------------- split-bf16 sim: sim = zn@zn^T via hi*hi + hi*lo + lo*hi
__global__ __launch_bounds__(256) void k_sims(const bf16* __restrict__ znhi,
                                              const bf16* __restrict__ znlo,
                                              float* __restrict__ sim)
{
  __shared__ bf16 sAh[128*32];
  __shared__ bf16 sAl[128*32];
  __shared__ bf16 sBh[128*32];
  __shared__ bf16 sBl[128*32];

  const int zi = blockIdx.z;
  const int w  = zi % 3;
  const int bt = zi / 3;
  const int b  = bt / T_;
  const int t  = bt % T_;
  if (w > t) return;                       // masked region — never read by topk
  const int tw = t - w;
  const int arow0 = bt*M_ + blockIdx.y*128;
  const int brow0 = (b*T_ + tw)*M_ + blockIdx.x*128;

  const bf16* Ah = znhi + (size_t)arow0*D_;
  const bf16* Al = znlo + (size_t)arow0*D_;
  const bf16* Bh = znhi + (size_t)brow0*D_;
  const bf16* Bl = znlo + (size_t)brow0*D_;

  v4f acc[4][4];
  #pragma unroll
  for (int i = 0; i < 4; ++i)
    #pragma unroll
    for (int j = 0; j < 4; ++j) acc[i][j] = (v4f){0.f,0.f,0.f,0.f};

  const int tid  = threadIdx.x;
  const int lane = tid & 63;
  const int wave = tid >> 6;
  const int quad = lane >> 4;
  const int l15  = lane & 15;
  const int wr = (wave >> 1) * 64;
  const int wc = (wave & 1) * 64;

  const int r0 = tid >> 2, g0 = (tid & 3) ^ ((r0 >> 1) & 3);
  const int c1 = tid + 256;
  const int r1 = c1 >> 2,  g1 = (c1 & 3) ^ ((r1 >> 1) & 3);
  const size_t o0 = (size_t)r0*D_ + g0*8;
  const size_t o1 = (size_t)r1*D_ + g1*8;

  int aoff[4], boff[4];
  #pragma unroll
  for (int i = 0; i < 4; ++i) {
    int ra = wr + i*16 + l15;
    aoff[i] = (ra*4 + (quad ^ ((ra >> 1) & 3))) * 8;
    int rb = wc + i*16 + l15;
    boff[i] = (rb*4 + (quad ^ ((rb >> 1) & 3))) * 8;
  }

  for (int k0 = 0; k0 < D_; k0 += 32) {
    __syncthreads();
    async16(Ah + o0 + k0, sAh + tid*8);
    async16(Ah + o1 + k0, sAh + c1*8);
    async16(Al + o0 + k0, sAl + tid*8);
    async16(Al + o1 + k0, sAl + c1*8);
    async16(Bh + o0 + k0, sBh + tid*8);
    async16(Bh + o1 + k0, sBh + c1*8);
    async16(Bl + o0 + k0, sBl + tid*8);
    async16(Bl + o1 + k0, sBl + c1*8);
    __syncthreads();
    v8s ah[4], al[4], bh[4], bl[4];
    #pragma unroll
    for (int i = 0; i < 4; ++i) {
      ah[i] = *(const v8s*)(sAh + aoff[i]);
      al[i] = *(const v8s*)(sAl + aoff[i]);
      bh[i] = *(const v8s*)(sBh + boff[i]);
      bl[i] = *(const v8s*)(sBl + boff[i]);
    }
    #pragma unroll
    for (int mi = 0; mi < 4; ++mi)
      #pragma unroll
      for (int ni = 0; ni < 4; ++ni) {
        acc[mi][ni] = __builtin_amdgcn_mfma_f32_16x16x32_bf16(ah[mi], bh[ni], acc[mi][ni], 0, 0, 0);
        acc[mi][ni] = __builtin_amdgcn_mfma_f32_16x16x32_bf16(ah[mi], bl[ni], acc[mi][ni], 0, 0, 0);
        acc[mi][ni] = __builtin_amdgcn_mfma_f32_16x16x32_bf16(al[mi], bh[ni], acc[mi][ni], 0, 0, 0);
      }
  }

  float* C = sim + (size_t)bt*M_*NC_;
  const int rowbase = blockIdx.y*128 + wr;
  const int colbase = w*M_ + blockIdx.x*128 + wc;
  #pragma unroll
  for (int ni = 0; ni < 4; ++ni) {
    const int col = colbase + ni*16 + l15;
    #pragma unroll
    for (int mi = 0; mi < 4; ++mi) {
      const int rowb = rowbase + mi*16 + quad*4;
      #pragma unroll
      for (int reg = 0; reg < 4; ++reg)
        C[(size_t)(rowb+reg)*NC_ + col] = acc[mi][ni][reg];
    }
  }
}

// ---------------- small kernels ----------------

__global__ __launch_bounds__(256) void k_cast(const float* __restrict__ src,
                                              bf16* __restrict__ dst, int n4) {
  int i = blockIdx.x*256 + threadIdx.x;
  if (i < n4) {
    float4 v = ((const float4*)src)[i];
    bf16* p = dst + (size_t)i*4;
    p[0] = __float2bfloat16(v.x); p[1] = __float2bfloat16(v.y);
    p[2] = __float2bfloat16(v.z); p[3] = __float2bfloat16(v.w);
  }
}

__global__ __launch_bounds__(256) void k_colsum(const float* __restrict__ Wk,
                                                float* __restrict__ wk_sum) {
  int d = blockIdx.x*256 + threadIdx.x;
  float s = 0.f;
  for (int i = 0; i < D_; ++i) s += Wk[(size_t)i*D_ + d];
  wk_sum[d] = s;
}

__global__ __launch_bounds__(64) void k_s0(const float* __restrict__ z,
                                           const float* __restrict__ Wattq,
                                           float* __restrict__ s0) {
  int bt = blockIdx.x;
  const float* zr = z + (size_t)bt*M_*D_;
  float p = 0.f;
  for (int d = threadIdx.x; d < D_; d += 64) p += zr[d]*Wattq[d];
  for (int o = 32; o; o >>= 1) p += __shfl_down(p, o, 64);
  if (threadIdx.x == 0) s0[bt] = p;
}

// kh[r] = z[r] . wk_sum   (wave per row)
__global__ __launch_bounds__(256) void k_kh(const float* __restrict__ z,
                                            const float* __restrict__ wks,
                                            float* __restrict__ kh) {
  int wave = threadIdx.x >> 6, l = threadIdx.x & 63;
  int r = blockIdx.x*4 + wave;
  const float* zp = z + (size_t)r*D_ + l*16;
  const float* wp = wks + l*16;
  float p = 0.f;
  #pragma unroll
  for (int j = 0; j < 4; ++j) {
    float4 a = *(const float4*)(zp + j*4);
    float4 b = *(const float4*)(wp + j*4);
    p += a.x*b.x + a.y*b.y + a.z*b.z + a.w*b.w;
  }
  for (int o = 32; o; o >>= 1) p += __shfl_down(p, o, 64);
  if (l == 0) kh[r] = p;
}

// normalize z row, split zn into bf16 hi+lo
__global__ __launch_bounds__(256) void k_znsplit(const float* __restrict__ z,
                                                 bf16* __restrict__ znhi,
                                                 bf16* __restrict__ znlo) {
  int row = blockIdx.x, tid = threadIdx.x;
  const float* zr = z + (size_t)row*D_;
  int d = tid*4;
  float4 v = *(const float4*)(zr + d);
  float ss = v.x*v.x + v.y*v.y + v.z*v.z + v.w*v.w;
  for (int o=32;o;o>>=1) ss += __shfl_down(ss,o,64);
  __shared__ float ps[4];
  if ((tid&63)==0) ps[tid>>6] = ss;
  __syncthreads();
  float s = ps[0]+ps[1]+ps[2]+ps[3];
  float rn = 1.0f / fmaxf(sqrtf(s), 1e-12f);
  float zn[4] = {v.x*rn, v.y*rn, v.z*rn, v.w*rn};
  bf16 hi[4], lo[4];
  #pragma unroll
  for (int j = 0; j < 4; ++j) {
    hi[j] = __float2bfloat16(zn[j]);
    lo[j] = __float2bfloat16(zn[j] - b2f(*(short*)&hi[j]));
  }
  *(short4*)(znhi + (size_t)row*D_ + d) = *(short4*)hi;
  *(short4*)(znlo + (size_t)row*D_ + d) = *(short4*)lo;
}

// wave-per-row: top-8 -> att softmax -> alpha -> kbar(bf16) = sum alpha_k z_k
__global__ __launch_bounds__(256) void k_topk(
    const float* __restrict__ sim, const float* __restrict__ kh,
    const float* __restrict__ s0, const bf16* __restrict__ zb,
    bf16* __restrict__ kbarb)
{
  const int wave = threadIdx.x >> 6, l = threadIdx.x & 63;
  const int r  = blockIdx.x*4 + wave;
  const int bt = r >> 9, m = r & 511;
  const int b  = bt >> 3, t = bt & 7;
  const float* srow = sim + (size_t)bt*M_*NC_ + (size_t)m*NC_;
  const int limit = (t >= 2) ? NC_ : ((t == 1) ? 2*M_ : M_);

  float v[24];
  #pragma unroll
  for (int j = 0; j < 24; ++j) {
    int i = j*64 + l;
    v[j] = (i < limit) ? srow[i] : -INFINITY;
  }

  float selv[KNN]; int seli[KNN];
  #pragma unroll
  for (int k = 0; k < KNN; ++k) {
    float bv = v[0]; int bj = 0;
    #pragma unroll
    for (int j = 1; j < 24; ++j)
      if (v[j] > bv) { bv = v[j]; bj = j; }     // strict > keeps min index in-lane
    int bi = bj*64 + l;
    #pragma unroll
    for (int o = 1; o < 64; o <<= 1) {
      float ov = __shfl_xor(bv, o, 64);
      int   oi = __shfl_xor(bi, o, 64);
      if (ov > bv || (ov == bv && oi < bi)) { bv = ov; bi = oi; }
    }
    selv[k] = bv; seli[k] = bi;
    if ((bi & 63) == l) {
      int jj = bi >> 6;
      #pragma unroll
      for (int j = 0; j < 24; ++j) if (j == jj) v[j] = -INFINITY;
    }
  }

  // attention weights from precomputed kh
  float khv = 0.f;
  if (l < KNN) {
    int idx = seli[l];
    int w = idx >> 9, n = idx & 511;
    int tt = t - w;
    khv = kh[(b*T_ + tt)*M_ + n];
  }
  float s0v = s0[bt];
  float att[KNN], mx = -INFINITY;
  #pragma unroll
  for (int k = 0; k < KNN; ++k) { att[k] = s0v * __shfl(khv, k, 64); mx = fmaxf(mx, att[k]); }
  float den = 0.f;
  #pragma unroll
  for (int k = 0; k < KNN; ++k) { att[k] = expf(att[k]-mx); den += att[k]; }
  float rden = 1.0f/den;
  float alpha[KNN];
  #pragma unroll
  for (int k = 0; k < KNN; ++k) alpha[k] = 0.5f*selv[k] + 0.5f*att[k]*rden;

  // kbar: 16 elems per lane
  const int d0 = l*16;
  float o[16];
  #pragma unroll
  for (int e = 0; e < 16; ++e) o[e] = 0.f;
  #pragma unroll
  for (int k = 0; k < KNN; ++k) {
    int idx = seli[k];
    int w = idx >> 9, n = idx & 511;
    int tt = t - w;
    const bf16* zp = zb + ((size_t)((b*T_ + tt)*M_ + n))*D_ + d0;
    v8s z0 = *(const v8s*)zp;
    v8s z1 = *(const v8s*)(zp + 8);
    float al = alpha[k];
    #pragma unroll
    for (int e = 0; e < 8; ++e) {
      o[e]   = fmaf(al, b2f(z0[e]), o[e]);
      o[8+e] = fmaf(al, b2f(z1[e]), o[8+e]);
    }
  }
  bf16* kp = kbarb + (size_t)r*D_ + d0;
  short outv[16];
  #pragma unroll
  for (int e = 0; e < 16; ++e) { bf16 h = __float2bfloat16(o[e]); outv[e] = *(short*)&h; }
  *(v8s*)kp       = *(v8s*)outv;
  *(v8s*)(kp + 8) = *(v8s*)(outv + 8);
}

// LN: read fp32 X, write bf16 Xb
__global__ __launch_bounds__(256) void k_ln(const float* __restrict__ X,
                                            const float* __restrict__ lw,
                                            const float* __restrict__ lb,
                                            bf16* __restrict__ Xb) {
  int r = blockIdx.x, tid = threadIdx.x;
  const float* xp = X + (size_t)r*D_;
  int d = tid*4;
  float4 v = *(const float4*)(xp + d);
  float s  = v.x+v.y+v.z+v.w;
  float ss = v.x*v.x+v.y*v.y+v.z*v.z+v.w*v.w;
  for (int o=32;o;o>>=1){ s += __shfl_down(s,o,64); ss += __shfl_down(ss,o,64); }
  __shared__ float rs[4], rss[4];
  if ((tid&63)==0){ rs[tid>>6]=s; rss[tid>>6]=ss; }
  __syncthreads();
  float mu  = (rs[0]+rs[1]+rs[2]+rs[3]) * (1.f/D_);
  float var = (rss[0]+rss[1]+rss[2]+rss[3]) * (1.f/D_) - mu*mu;
  float rstd = rsqrtf(var + 1e-5f);
  float4 w  = *(const float4*)(lw+d);
  float4 bb = *(const float4*)(lb+d);
  bf16* op = Xb + (size_t)r*D_ + d;
  op[0] = __float2bfloat16((v.x-mu)*rstd*w.x + bb.x);
  op[1] = __float2bfloat16((v.y-mu)*rstd*w.y + bb.y);
  op[2] = __float2bfloat16((v.z-mu)*rstd*w.z + bb.z);
  op[3] = __float2bfloat16((v.w-mu)*rstd*w.w + bb.w);
}

__global__ __launch_bounds__(256) void k_gru(
    const float* __restrict__ gi, const float* __restrict__ gh,
    float* __restrict__ mem, bf16* __restrict__ memb,
    bf16* __restrict__ memhb, int t)
{
  int gid = blockIdx.x*256 + threadIdx.x;
  int row = gid >> 10, h = gid & 1023;
  int b = row >> 9, m = row & 511;
  size_t girow = ((size_t)((b*T_ + t)*M_ + m))*(3*H_);
  float ir  = gi[girow + h];
  float iz  = gi[girow + H_ + h];
  float in_ = gi[girow + 2*H_ + h];
  size_t ghrow = (size_t)row*(3*H_);
  float hr = gh[ghrow + h];
  float hz = gh[ghrow + H_ + h];
  float hn = gh[ghrow + 2*H_ + h];
  float rg = 1.f/(1.f+expf(-(ir+hr)));
  float zg = 1.f/(1.f+expf(-(iz+hz)));
  float n  = tanhf(in_ + rg*hn);
  float mold = mem[gid];
  float mnew = (1.f-zg)*n + zg*mold;
  mem[gid] = mnew;
  memb[gid] = __float2bfloat16(mnew);
  memhb[((size_t)((b*T_ + t)*M_ + m))*H_ + h] = __float2bfloat16(mnew);
}

extern "C" void kernel_launch(void* const* d_in, const int* in_sizes, int n_in,
                              void* d_out, int out_size, void* d_ws, size_t ws_size,
                              hipStream_t stream) {
  (void)in_sizes; (void)n_in; (void)out_size; (void)ws_size;
  const float* z      = (const float*)d_in[0];
  const float* Wq     = (const float*)d_in[1];
  const float* Wv     = (const float*)d_in[2];
  const float* Wout   = (const float*)d_in[3];
  const float* ln_w   = (const float*)d_in[4];
  const float* ln_b   = (const float*)d_in[5];
  const float* Watt_q = (const float*)d_in[6];
  const float* Watt_k = (const float*)d_in[7];
  const float* W_ih   = (const float*)d_in[8];
  const float* W_hh   = (const float*)d_in[9];
  const float* b_ih   = (const float*)d_in[10];
  const float* b_hh   = (const float*)d_in[11];
  const float* W_mf   = (const float*)d_in[12];
  const float* b_mf   = (const float*)d_in[13];
  float* out = (float*)d_out;
  float* ws  = (float*)d_ws;

  // workspace (float offsets), heavy overlaying:
  //  [0 .. 25165824): GI (8192x3072 f32); sim aliases first 12582912 (dead after
  //                   topk); X aliases first 8388608 (written post-topk, dead post-LN)
  float* GI    = ws;
  float* sim   = ws;
  float* X     = ws;
  float* gs    = ws + 25165824;             // 3,145,728 f
  float* mem   = ws + 28311552;             // 1,048,576 f
  bf16*  Xb    = (bf16*)(ws + 29360128);    // 8,388,608 bf16 — znhi aliases (dead pre-LN)
  bf16*  znhi  = Xb;
  bf16*  zb    = (bf16*)(ws + 33554432);    // 8,388,608 bf16
  bf16*  kbarb = (bf16*)(ws + 37748736);    // 8,388,608 bf16 (alias INPb)
  bf16*  INPb  = kbarb;
  bf16*  memb  = (bf16*)(ws + 41943040);    // 1,048,576 bf16
  bf16*  memhb = (bf16*)(ws + 42467328);    // 8,388,608 bf16 — znlo aliases (dead pre-GRU)
  bf16*  znlo  = memhb;
  bf16*  Wqb   = (bf16*)(ws + 46661632);
  bf16*  Wvb   = Wqb + 1048576;
  bf16*  Woutb = Wqb + 2097152;
  bf16*  Wihb  = Wqb + 3145728;
  bf16*  Whhb  = Wqb + 6291456;
  bf16*  Wmfb  = Wqb + 9437184;
  float* wks   = ws + 51904512;             // 1024
  float* s0    = ws + 51905536;             // 16
  float* kh    = ws + 51905552;             // 8192
  // end: 51,913,744 floats ~ 207.7 MiB

  // weight + z casts
  k_cast<<<dim3(1024), dim3(256), 0, stream>>>(Wq,   Wqb,   262144);
  k_cast<<<dim3(1024), dim3(256), 0, stream>>>(Wv,   Wvb,   262144);
  k_cast<<<dim3(1024), dim3(256), 0, stream>>>(Wout, Woutb, 262144);
  k_cast<<<dim3(3072), dim3(256), 0, stream>>>(W_ih, Wihb,  786432);
  k_cast<<<dim3(3072), dim3(256), 0, stream>>>(W_hh, Whhb,  786432);
  k_cast<<<dim3(1024), dim3(256), 0, stream>>>(W_mf, Wmfb,  262144);
  k_cast<<<dim3(8192), dim3(256), 0, stream>>>(z,    zb,   2097152);

  k_colsum <<<dim3(4),    dim3(256), 0, stream>>>(Watt_k, wks);
  k_s0     <<<dim3(16),   dim3(64),  0, stream>>>(z, Watt_q, s0);
  k_kh     <<<dim3(2048), dim3(256), 0, stream>>>(z, wks, kh);
  k_znsplit<<<dim3(8192), dim3(256), 0, stream>>>(z, znhi, znlo);

  // sim via error-compensated bf16 MFMA (hi*hi + hi*lo + lo*hi ~ fp32 to ~1e-7)
  k_sims<<<dim3(4,4,48), dim3(256), 0, stream>>>(znhi, znlo, sim);

  // wave-per-row topk + attention + kbar (bf16)
  k_topk<<<dim3(2048), dim3(256), 0, stream>>>(sim, kh, s0, zb, kbarb);

  // X = kbar@Wv^T + z@Wq^T  (fp32 out)
  k_bgemm<true,false,false,false><<<dim3(8,64), dim3(256), 0, stream>>>(
      kbarb, Wvb, zb, Wqb, nullptr, nullptr, X, D_, D_);

  // LN -> Xb (bf16)
  k_ln<<<dim3(8192), dim3(256), 0, stream>>>(X, ln_w, ln_b, Xb);

  // INP = X@Wout^T -> bf16
  k_bgemm<false,false,false,true><<<dim3(8,64), dim3(256), 0, stream>>>(
      Xb, Woutb, nullptr, nullptr, nullptr, nullptr, INPb, D_, D_);

  // GI = INP@W_ih^T + b_ih (fp32, overlays sim/X region)
  k_bgemm<false,true,false,false><<<dim3(24,64), dim3(256), 0, stream>>>(
      INPb, Wihb, nullptr, nullptr, b_ih, nullptr, GI, 3*H_, D_);

  hipMemsetAsync(mem,  0, (size_t)1048576*sizeof(float), stream);
  hipMemsetAsync(memb, 0, (size_t)1048576*sizeof(bf16),  stream);

  for (int t = 0; t < T_; ++t) {
    // gs = mem@W_hh^T + b_hh (1024x3072)
    k_bgemm<false,true,false,false><<<dim3(24,8), dim3(256), 0, stream>>>(
        memb, Whhb, nullptr, nullptr, b_hh, nullptr, gs, 3*H_, H_);
    k_gru<<<dim3(4096), dim3(256), 0, stream>>>(GI, gs, mem, memb, memhb, t);
  }

  // OUT = z + memh@W_mf^T + b_mf  (single flat 8192x1024 GEMM)
  k_bgemm<false,true,true,false><<<dim3(8,64), dim3(256), 0, stream>>>(
      memhb, Wmfb, nullptr, nullptr, b_mf, z, out, D_, H_);

  hipMemcpyAsync(out + (size_t)B_*T_*M_*D_, mem, (size_t)1048576*sizeof(float),
                 hipMemcpyDeviceToDevice, stream);
}